// Round 1
// baseline (205.141 us; speedup 1.0000x reference)
//
#include <hip/hip_runtime.h>

// Sizes fixed by the reference.
#define BB 4
#define SS 4096
#define DM 1024
#define HID 64
#define KTOP 204
static constexpr size_t PATTERN_N = (size_t)BB * SS * SS;  // 67108864

typedef float f4 __attribute__((ext_vector_type(4)));

// ---------------------------------------------------------------------------
// K1: scores[b,s] = relu(emb[b,s,:] @ W1 + b1) @ W2 + b2
// 512 blocks x 256 threads; each block owns 32 tokens; lane = hidden unit.
// emb chunk staged in LDS (32 tokens x 64 dims); W1 re-read per block but
// L1/L2 resident (16 KB working set per chunk).
// ---------------------------------------------------------------------------
__global__ __launch_bounds__(256) void k1_scores(
    const float* __restrict__ emb, const float* __restrict__ W1,
    const float* __restrict__ b1, const float* __restrict__ W2,
    const float* __restrict__ b2, float* __restrict__ scores) {
  __shared__ __align__(16) float lds[32][64];
  const int tid = threadIdx.x;
  const int h   = tid & 63;   // hidden unit (lane)
  const int wv  = tid >> 6;   // wave id 0..3, owns tokens wv*8..wv*8+7
  const int tok0 = blockIdx.x * 32;

  float4 acc[8];
#pragma unroll
  for (int t = 0; t < 8; ++t) acc[t] = make_float4(0.f, 0.f, 0.f, 0.f);

  for (int cb = 0; cb < DM; cb += 64) {
    // stage 32x64 f32 chunk: 512 float4s, 2 per thread, coalesced
#pragma unroll
    for (int q = 0; q < 2; ++q) {
      int f  = tid + q * 256;
      int r  = f >> 4;        // token row (16 float4 per row)
      int c4 = f & 15;
      *reinterpret_cast<float4*>(&lds[r][c4 * 4]) =
          *reinterpret_cast<const float4*>(
              &emb[(size_t)(tok0 + r) * DM + cb + c4 * 4]);
    }
    __syncthreads();
#pragma unroll
    for (int dd = 0; dd < 64; dd += 4) {
      const int d = cb + dd;
      const float w0 = W1[(size_t)(d + 0) * HID + h];
      const float w1 = W1[(size_t)(d + 1) * HID + h];
      const float w2 = W1[(size_t)(d + 2) * HID + h];
      const float w3 = W1[(size_t)(d + 3) * HID + h];
#pragma unroll
      for (int t = 0; t < 8; ++t) {
        float4 e = *reinterpret_cast<const float4*>(&lds[wv * 8 + t][dd]);
        acc[t].x = fmaf(e.x, w0, acc[t].x);
        acc[t].y = fmaf(e.y, w1, acc[t].y);
        acc[t].z = fmaf(e.z, w2, acc[t].z);
        acc[t].w = fmaf(e.w, w3, acc[t].w);
      }
    }
    __syncthreads();
  }

  const float bb1 = b1[h];
  const float ww2 = W2[h];
  const float bb2 = b2[0];
#pragma unroll
  for (int t = 0; t < 8; ++t) {
    float s = (acc[t].x + acc[t].y) + (acc[t].z + acc[t].w);
    s += bb1;
    s = s > 0.f ? s : 0.f;        // relu
    float c = s * ww2;            // per-hidden contribution
#pragma unroll
    for (int m = 32; m > 0; m >>= 1) c += __shfl_xor(c, m, 64);
    if (h == 0) scores[tok0 + wv * 8 + t] = c + bb2;
  }
}

// ---------------------------------------------------------------------------
// K2: exact top-k by rank counting. rank(i) = #{j: s_j>s_i} + #{j<i: s_j==s_i}
// reproduces jax.lax.top_k ordering (descending, ties -> lower index first).
// 64 blocks (16 per batch) x 256 threads, one query index per thread.
// Writes indices AS FLOAT into d_out's index region.
// ---------------------------------------------------------------------------
__global__ __launch_bounds__(256) void k2_topk(
    const float* __restrict__ scores, float* __restrict__ out_idx) {
  __shared__ __align__(16) float sc[SS];
  const int tid = threadIdx.x;
  const int b = blockIdx.x >> 4;
  const int i = ((blockIdx.x & 15) << 8) + tid;
  const float* row = scores + (size_t)b * SS;
#pragma unroll
  for (int q = 0; q < 4; ++q) {
    int f = tid + q * 256;  // float4 index
    *reinterpret_cast<float4*>(&sc[f * 4]) =
        *reinterpret_cast<const float4*>(&row[f * 4]);
  }
  __syncthreads();
  const float si = sc[i];
  const float4* s4 = reinterpret_cast<const float4*>(sc);
  int cnt = 0;
  for (int j4 = 0; j4 < SS / 4; ++j4) {
    float4 v = s4[j4];       // broadcast LDS read (all lanes same addr)
    int j = j4 * 4;
    cnt += (int)(v.x > si) + (int)((v.x == si) & (j + 0 < i));
    cnt += (int)(v.y > si) + (int)((v.y == si) & (j + 1 < i));
    cnt += (int)(v.z > si) + (int)((v.z == si) & (j + 2 < i));
    cnt += (int)(v.w > si) + (int)((v.w == si) & (j + 3 < i));
  }
  if (cnt < KTOP) out_idx[b * KTOP + cnt] = (float)i;
}

// ---------------------------------------------------------------------------
// K3: attention_pattern[b,i,:] = col_mask[b,:] for all i.
// 512 blocks x 256 threads; block owns 32 rows of one batch. Mask built in
// LDS from the (already final) float indices, held in registers, streamed
// out with nontemporal float4 stores (268 MB -> write-BW bound).
// ---------------------------------------------------------------------------
__global__ __launch_bounds__(256) void k3_pattern(
    const float* __restrict__ out_idx, float* __restrict__ pat) {
  __shared__ __align__(16) float mask[SS];
  const int tid = threadIdx.x;
  const int b  = blockIdx.x >> 7;           // 128 blocks per batch
  const int r0 = (blockIdx.x & 127) * 32;
  const f4 zero = (f4){0.f, 0.f, 0.f, 0.f};
#pragma unroll
  for (int q = 0; q < 4; ++q) {
    int f = tid + q * 256;
    *reinterpret_cast<f4*>(&mask[f * 4]) = zero;
  }
  __syncthreads();
  if (tid < KTOP) {
    int c = (int)out_idx[b * KTOP + tid];
    mask[c] = 1.0f / (float)KTOP;
  }
  __syncthreads();
  // hold this thread's 4 mask float4s in registers
  const f4 m0 = *reinterpret_cast<const f4*>(&mask[(tid)*4]);
  const f4 m1 = *reinterpret_cast<const f4*>(&mask[(tid + 256) * 4]);
  const f4 m2 = *reinterpret_cast<const f4*>(&mask[(tid + 512) * 4]);
  const f4 m3 = *reinterpret_cast<const f4*>(&mask[(tid + 768) * 4]);
  for (int r = 0; r < 32; ++r) {
    f4* p4 = reinterpret_cast<f4*>(pat + ((size_t)b * SS + r0 + r) * SS);
    __builtin_nontemporal_store(m0, &p4[tid]);
    __builtin_nontemporal_store(m1, &p4[tid + 256]);
    __builtin_nontemporal_store(m2, &p4[tid + 512]);
    __builtin_nontemporal_store(m3, &p4[tid + 768]);
  }
}

extern "C" void kernel_launch(void* const* d_in, const int* in_sizes, int n_in,
                              void* d_out, int out_size, void* d_ws,
                              size_t ws_size, hipStream_t stream) {
  const float* emb = (const float*)d_in[0];
  const float* W1  = (const float*)d_in[1];
  const float* b1  = (const float*)d_in[2];
  const float* W2  = (const float*)d_in[3];
  const float* b2  = (const float*)d_in[4];
  float* out = (float*)d_out;
  float* pat     = out;              // [B,S,S] pattern
  float* out_idx = out + PATTERN_N;  // [B,KTOP] indices as float
  // scores scratch lives in the first 64 KB of the pattern region;
  // K3 overwrites it afterwards (kernels are stream-ordered).
  float* scores = out;

  k1_scores<<<dim3((BB * SS) / 32), dim3(256), 0, stream>>>(emb, W1, b1, W2,
                                                            b2, scores);
  k2_topk<<<dim3(BB * (SS / 256)), dim3(256), 0, stream>>>(scores, out_idx);
  k3_pattern<<<dim3((BB * SS) / 32), dim3(256), 0, stream>>>(out_idx, pat);
}

// Round 2
// 179.318 us; speedup vs baseline: 1.1440x; 1.1440x over previous
//
#include <hip/hip_runtime.h>

// Sizes fixed by the reference.
#define BB 4
#define SS 4096
#define DM 1024
#define HID 64
#define KTOP 204
static constexpr size_t PATTERN_N = (size_t)BB * SS * SS;  // 67108864

typedef float f4 __attribute__((ext_vector_type(4)));

// ---------------------------------------------------------------------------
// K1: scores[b,s] = relu(emb[b,s,:] @ W1 + b1) @ W2 + b2
// 512 blocks x 256 threads. lane = hidden unit h (64 = wave width); each wave
// owns 8 tokens. NO LDS: embedding values are wave-uniform (same for all h)
// -> uniform loads (scalar/broadcast, ~16B traffic each); W1[d][h] is the
// per-lane load, 256B/wave, L1-resident since all waves walk d in lockstep.
// d-chunk of 8: 8 W1 loads + 16 uniform e-loads clustered, then 64 FMAs.
// ---------------------------------------------------------------------------
__global__ __launch_bounds__(256) void k1_scores(
    const float* __restrict__ emb, const float* __restrict__ W1,
    const float* __restrict__ b1, const float* __restrict__ W2,
    const float* __restrict__ b2, float* __restrict__ scores) {
  const int tid = threadIdx.x;
  const int h = tid & 63;
  const int wv = __builtin_amdgcn_readfirstlane(tid >> 6);  // wave-uniform
  const int tok0 = blockIdx.x * 32 + wv * 8;
  const float* __restrict__ eb = emb + (size_t)tok0 * DM;  // uniform base

  float acc[8];
#pragma unroll
  for (int t = 0; t < 8; ++t) acc[t] = 0.f;

  const float* __restrict__ wp = W1 + h;

#pragma unroll 1
  for (int d = 0; d < DM; d += 8) {
    float w[8];
#pragma unroll
    for (int j = 0; j < 8; ++j) w[j] = wp[(size_t)(d + j) * HID];
    f4 e0[8], e1[8];
#pragma unroll
    for (int t = 0; t < 8; ++t) {
      e0[t] = *reinterpret_cast<const f4*>(eb + (size_t)t * DM + d);
      e1[t] = *reinterpret_cast<const f4*>(eb + (size_t)t * DM + d + 4);
    }
#pragma unroll
    for (int t = 0; t < 8; ++t) {
      acc[t] = fmaf(e0[t].x, w[0], acc[t]);
      acc[t] = fmaf(e0[t].y, w[1], acc[t]);
      acc[t] = fmaf(e0[t].z, w[2], acc[t]);
      acc[t] = fmaf(e0[t].w, w[3], acc[t]);
      acc[t] = fmaf(e1[t].x, w[4], acc[t]);
      acc[t] = fmaf(e1[t].y, w[5], acc[t]);
      acc[t] = fmaf(e1[t].z, w[6], acc[t]);
      acc[t] = fmaf(e1[t].w, w[7], acc[t]);
    }
  }

  const float bb1 = b1[h];
  const float ww2 = W2[h];
  const float bb2 = b2[0];
#pragma unroll
  for (int t = 0; t < 8; ++t) {
    float s = acc[t] + bb1;
    s = s > 0.f ? s : 0.f;  // relu
    float c = s * ww2;      // per-hidden contribution
#pragma unroll
    for (int m = 32; m > 0; m >>= 1) c += __shfl_xor(c, m, 64);
    if (h == 0) scores[tok0 + t] = c + bb2;
  }
}

// ---------------------------------------------------------------------------
// K2: exact top-k by rank counting. rank(i) = #{j: s_j>s_i} + #{j<i: s_j==s_i}
// reproduces jax.lax.top_k ordering (descending, ties -> lower index first).
// 256 blocks x 256 threads: block = (batch, 64-wide i-chunk); the 4 waves
// split the j-range 4 ways, tree-combined through LDS. All j-reads are
// wave-uniform broadcasts from LDS.
// ---------------------------------------------------------------------------
__global__ __launch_bounds__(256) void k2_topk(
    const float* __restrict__ scores, float* __restrict__ out_idx) {
  __shared__ __align__(16) float sc[SS];
  __shared__ int red[256];
  const int tid = threadIdx.x;
  const int b = blockIdx.x >> 6;
  const int ic = blockIdx.x & 63;
  const float* row = scores + (size_t)b * SS;
#pragma unroll
  for (int q = 0; q < 4; ++q) {
    int f = tid + q * 256;  // float4 index
    *reinterpret_cast<f4*>(&sc[f * 4]) =
        *reinterpret_cast<const f4*>(&row[f * 4]);
  }
  __syncthreads();
  const int il = tid & 63;
  const int part = tid >> 6;  // j quarter (wave-uniform)
  const int i = ic * 64 + il;
  const float si = sc[i];
  const f4* s4 = reinterpret_cast<const f4*>(sc);
  int cnt = 0;
  for (int j4 = part * 256; j4 < part * 256 + 256; ++j4) {
    f4 v = s4[j4];  // broadcast LDS read
    int j = j4 * 4;
    cnt += (int)(v.x > si) + (int)((v.x == si) & (j + 0 < i));
    cnt += (int)(v.y > si) + (int)((v.y == si) & (j + 1 < i));
    cnt += (int)(v.z > si) + (int)((v.z == si) & (j + 2 < i));
    cnt += (int)(v.w > si) + (int)((v.w == si) & (j + 3 < i));
  }
  red[tid] = cnt;
  __syncthreads();
  if (tid < 64) {
    int tot = red[tid] + red[tid + 64] + red[tid + 128] + red[tid + 192];
    if (tot < KTOP) out_idx[b * KTOP + tot] = (float)(ic * 64 + tid);
  }
}

// ---------------------------------------------------------------------------
// K3: attention_pattern[b,i,:] = col_mask[b,:] for all i.
// 1024 blocks x 256 threads; block owns 16 rows of one batch (4 blocks/CU).
// Mask built once per block in LDS, held in registers, streamed out with
// nontemporal float4 stores (268 MB -> write-BW bound, ~7 TB/s ceiling).
// ---------------------------------------------------------------------------
__global__ __launch_bounds__(256) void k3_pattern(
    const float* __restrict__ out_idx, float* __restrict__ pat) {
  __shared__ __align__(16) float mask[SS];
  const int tid = threadIdx.x;
  const int b  = blockIdx.x >> 8;            // 256 blocks per batch
  const int r0 = (blockIdx.x & 255) * 16;
  const f4 zero = (f4){0.f, 0.f, 0.f, 0.f};
#pragma unroll
  for (int q = 0; q < 4; ++q) {
    int f = tid + q * 256;
    *reinterpret_cast<f4*>(&mask[f * 4]) = zero;
  }
  __syncthreads();
  if (tid < KTOP) {
    int c = (int)out_idx[b * KTOP + tid];
    mask[c] = 1.0f / (float)KTOP;
  }
  __syncthreads();
  const f4 m0 = *reinterpret_cast<const f4*>(&mask[(tid)*4]);
  const f4 m1 = *reinterpret_cast<const f4*>(&mask[(tid + 256) * 4]);
  const f4 m2 = *reinterpret_cast<const f4*>(&mask[(tid + 512) * 4]);
  const f4 m3 = *reinterpret_cast<const f4*>(&mask[(tid + 768) * 4]);
  for (int r = 0; r < 16; ++r) {
    f4* p4 = reinterpret_cast<f4*>(pat + ((size_t)b * SS + r0 + r) * SS);
    __builtin_nontemporal_store(m0, &p4[tid]);
    __builtin_nontemporal_store(m1, &p4[tid + 256]);
    __builtin_nontemporal_store(m2, &p4[tid + 512]);
    __builtin_nontemporal_store(m3, &p4[tid + 768]);
  }
}

extern "C" void kernel_launch(void* const* d_in, const int* in_sizes, int n_in,
                              void* d_out, int out_size, void* d_ws,
                              size_t ws_size, hipStream_t stream) {
  const float* emb = (const float*)d_in[0];
  const float* W1  = (const float*)d_in[1];
  const float* b1  = (const float*)d_in[2];
  const float* W2  = (const float*)d_in[3];
  const float* b2  = (const float*)d_in[4];
  float* out = (float*)d_out;
  float* pat     = out;              // [B,S,S] pattern
  float* out_idx = out + PATTERN_N;  // [B,KTOP] indices as float
  // scores scratch lives in the first 64 KB of the pattern region;
  // K3 overwrites it afterwards (kernels are stream-ordered).
  float* scores = out;

  k1_scores<<<dim3((BB * SS) / 32), dim3(256), 0, stream>>>(emb, W1, b1, W2,
                                                            b2, scores);
  k2_topk<<<dim3(BB * (SS / 64)), dim3(256), 0, stream>>>(scores, out_idx);
  k3_pattern<<<dim3((BB * SS) / 16), dim3(256), 0, stream>>>(out_idx, pat);
}